// Round 3
// baseline (552.485 us; speedup 1.0000x reference)
//
#include <hip/hip_runtime.h>

// Local 8x8 window autocorrelation, stride 4.
// x: (B, C, H, W) fp32 -> out: (B, C, nH, nW, KH, KW) fp32
// out[n, dy, dx] = sum_{i,j} p[i+dy-4][j+dx-4] * p[i][j]  (zero outside window)
//
// One thread per window (densest: 2304 FMA / 16 loads per window, patch read
// once). Outputs staged through LDS in two 32-float halves so global stores
// are full-line coalesced (R1 showed direct 256B-stride dwordx4 stores cost
// 4.5x write amplification). __launch_bounds__(128,4) caps VGPR at 128
// (R1's unconstrained build used 256 -> 9% occupancy).

constexpr int KH = 8, KW = 8, SH = 4, SW = 4;
constexpr int B = 8, C = 64, H = 96, W = 96;
constexpr int nH = (H - KH) / SH + 1;  // 23
constexpr int nW = (W - KW) / SW + 1;  // 23
constexpr int NWIN = B * C * nH * nW;  // 270848 = 128 * 2116
constexpr int TPB = 128;
constexpr int LDS_STRIDE = 33;         // 32 floats + 1 pad -> conflict-free

__global__ __launch_bounds__(TPB, 4) void
local_autocorr_kernel(const float* __restrict__ x, float* __restrict__ out) {
    __shared__ float lds[TPB * LDS_STRIDE];  // 16896 B

    const int tid = threadIdx.x;
    const int n = blockIdx.x * TPB + tid;

    const int w  = n % nW;
    const int tt = n / nW;
    const int h  = tt % nH;
    const int bc = tt / nH;  // b*C + c

    const float* xp = x + ((size_t)bc * H + (size_t)h * SH) * W + (size_t)w * SW;

    // Load the 8x8 patch into registers (static indexing only).
    float p[64];
#pragma unroll
    for (int r = 0; r < 8; ++r) {
        const float4 lo = *reinterpret_cast<const float4*>(xp + (size_t)r * W);
        const float4 hi = *reinterpret_cast<const float4*>(xp + (size_t)r * W + 4);
        p[r * 8 + 0] = lo.x; p[r * 8 + 1] = lo.y;
        p[r * 8 + 2] = lo.z; p[r * 8 + 3] = lo.w;
        p[r * 8 + 4] = hi.x; p[r * 8 + 5] = hi.y;
        p[r * 8 + 6] = hi.z; p[r * 8 + 7] = hi.w;
    }

    float* obase = out + (size_t)blockIdx.x * TPB * 64;

#pragma unroll
    for (int half = 0; half < 2; ++half) {
        // Compute 4 dy rows, stash each in LDS.
#pragma unroll
        for (int dq = 0; dq < 4; ++dq) {
            const int dy = half * 4 + dq;
            const int oy = dy - 4;  // compile-time after unroll
            float accs[8];
#pragma unroll
            for (int dx = 0; dx < 8; ++dx) {
                const int ox = dx - 4;
                float acc = 0.0f;
#pragma unroll
                for (int i = 0; i < 8; ++i) {
                    if (i + oy < 0 || i + oy >= 8) continue;  // static DCE
#pragma unroll
                    for (int j = 0; j < 8; ++j) {
                        if (j + ox < 0 || j + ox >= 8) continue;
                        acc = fmaf(p[(i + oy) * 8 + (j + ox)], p[i * 8 + j], acc);
                    }
                }
                accs[dx] = acc;
            }
            *reinterpret_cast<float4*>(&lds[tid * LDS_STRIDE + dq * 8]) =
                make_float4(accs[0], accs[1], accs[2], accs[3]);
            *reinterpret_cast<float4*>(&lds[tid * LDS_STRIDE + dq * 8 + 4]) =
                make_float4(accs[4], accs[5], accs[6], accs[7]);
        }
        __syncthreads();
        // Cooperative coalesced flush of this half (32 floats per window).
#pragma unroll
        for (int k = 0; k < 8; ++k) {
            const int flat4 = tid + k * TPB;   // 0..1023 float4 slots
            const int win   = flat4 >> 3;      // 0..127
            const int off4  = flat4 & 7;       // 0..7
            const float4 v = *reinterpret_cast<const float4*>(
                &lds[win * LDS_STRIDE + off4 * 4]);
            *reinterpret_cast<float4*>(
                obase + (size_t)win * 64 + half * 32 + off4 * 4) = v;
        }
        __syncthreads();  // protect LDS before next half overwrites it
    }
}

extern "C" void kernel_launch(void* const* d_in, const int* in_sizes, int n_in,
                              void* d_out, int out_size, void* d_ws, size_t ws_size,
                              hipStream_t stream) {
    const float* x = (const float*)d_in[0];
    float* out = (float*)d_out;

    const int blocks = NWIN / TPB;  // 2116, exact
    local_autocorr_kernel<<<blocks, TPB, 0, stream>>>(x, out);
}

// Round 4
// 121.405 us; speedup vs baseline: 4.5508x; 4.5508x over previous
//
#include <hip/hip_runtime.h>

// Local 8x8 window autocorrelation, stride 4.
// x: (B, C, H, W) fp32 -> out: (B, C, nH, nW, KH, KW) fp32
// out[n, dy, dx] = sum_{i,j} p[i+dy-4][j+dx-4] * p[i][j]  (zero outside window)
//
// One thread per window (2304 FMA / 16 loads per window). Outputs staged
// through LDS so global stores are full-line coalesced (R1: direct scattered
// dwordx4 stores -> 4.5x write amplification + store backpressure).
// NO min-waves launch-bounds arg: R3's (128,4) forced a 64-VGPR cap and
// spilled p[64] to scratch (780MB fetch / 883MB write, 552us).
// sched_barrier(0) after each dy row contains accumulator liveness so the
// scheduler doesn't fuse all 8 rows into one live set (R1 ballooned to 256).

constexpr int KH = 8, KW = 8, SH = 4, SW = 4;
constexpr int B = 8, C = 64, H = 96, W = 96;
constexpr int nH = (H - KH) / SH + 1;  // 23
constexpr int nW = (W - KW) / SW + 1;  // 23
constexpr int NWIN = B * C * nH * nW;  // 270848 = 128 * 2116
constexpr int TPB = 128;
constexpr int LDS_STRIDE = 33;         // 32 floats + 1 pad -> conflict-free

__global__ __launch_bounds__(TPB) void
local_autocorr_kernel(const float* __restrict__ x, float* __restrict__ out) {
    __shared__ float lds[TPB * LDS_STRIDE];  // 16896 B

    const int tid = threadIdx.x;
    const int n = blockIdx.x * TPB + tid;

    const int w  = n % nW;
    const int tt = n / nW;
    const int h  = tt % nH;
    const int bc = tt / nH;  // b*C + c

    const float* xp = x + ((size_t)bc * H + (size_t)h * SH) * W + (size_t)w * SW;

    // Load the 8x8 patch into registers (static indexing only).
    float p[64];
#pragma unroll
    for (int r = 0; r < 8; ++r) {
        const float4 lo = *reinterpret_cast<const float4*>(xp + (size_t)r * W);
        const float4 hi = *reinterpret_cast<const float4*>(xp + (size_t)r * W + 4);
        p[r * 8 + 0] = lo.x; p[r * 8 + 1] = lo.y;
        p[r * 8 + 2] = lo.z; p[r * 8 + 3] = lo.w;
        p[r * 8 + 4] = hi.x; p[r * 8 + 5] = hi.y;
        p[r * 8 + 6] = hi.z; p[r * 8 + 7] = hi.w;
    }

    float* obase = out + (size_t)blockIdx.x * TPB * 64;

#pragma unroll
    for (int half = 0; half < 2; ++half) {
        // Compute 4 dy rows, stash each in LDS.
#pragma unroll
        for (int dq = 0; dq < 4; ++dq) {
            const int dy = half * 4 + dq;
            const int oy = dy - 4;  // compile-time after unroll
            float accs[8];
#pragma unroll
            for (int dx = 0; dx < 8; ++dx) {
                const int ox = dx - 4;
                float acc = 0.0f;
#pragma unroll
                for (int i = 0; i < 8; ++i) {
                    if (i + oy < 0 || i + oy >= 8) continue;  // static DCE
#pragma unroll
                    for (int j = 0; j < 8; ++j) {
                        if (j + ox < 0 || j + ox >= 8) continue;
                        acc = fmaf(p[(i + oy) * 8 + (j + ox)], p[i * 8 + j], acc);
                    }
                }
                accs[dx] = acc;
            }
            *reinterpret_cast<float4*>(&lds[tid * LDS_STRIDE + dq * 8]) =
                make_float4(accs[0], accs[1], accs[2], accs[3]);
            *reinterpret_cast<float4*>(&lds[tid * LDS_STRIDE + dq * 8 + 4]) =
                make_float4(accs[4], accs[5], accs[6], accs[7]);
            // Contain liveness: keep each dy row's accumulators local so the
            // scheduler doesn't fuse all rows into one giant live set.
            __builtin_amdgcn_sched_barrier(0);
        }
        __syncthreads();
        // Cooperative coalesced flush of this half (32 floats per window).
#pragma unroll
        for (int k = 0; k < 8; ++k) {
            const int flat4 = tid + k * TPB;   // 0..1023 float4 slots
            const int win   = flat4 >> 3;      // 0..127
            const int off4  = flat4 & 7;       // 0..7
            const float4 v = *reinterpret_cast<const float4*>(
                &lds[win * LDS_STRIDE + off4 * 4]);
            *reinterpret_cast<float4*>(
                obase + (size_t)win * 64 + half * 32 + off4 * 4) = v;
        }
        __syncthreads();  // protect LDS before next half overwrites it
    }
}

extern "C" void kernel_launch(void* const* d_in, const int* in_sizes, int n_in,
                              void* d_out, int out_size, void* d_ws, size_t ws_size,
                              hipStream_t stream) {
    const float* x = (const float*)d_in[0];
    float* out = (float*)d_out;

    const int blocks = NWIN / TPB;  // 2116, exact
    local_autocorr_kernel<<<blocks, TPB, 0, stream>>>(x, out);
}

// Round 5
// 117.619 us; speedup vs baseline: 4.6972x; 1.0322x over previous
//
#include <hip/hip_runtime.h>

// Local 8x8 window autocorrelation, stride 4.
// x: (B, C, H, W) fp32 -> out: (B, C, nH, nW, KH, KW) fp32
// out[n, dy, dx] = sum_{i,j} p[i+dy-4][j+dx-4] * p[i][j]  (zero outside window)
//
// One thread per window (2304 FMA / 16 loads). Outputs staged in LDS and
// flushed so each wave store instruction covers FULL 256B-aligned window
// regions (1KB contiguous per instruction).
// Evidence trail: R1 (16B scattered stores) -> 4.7x write amplification;
// R4 (128B chunks with 128B gaps, halves separated in time) -> 3.0x write +
// 3.0x fetch amplification; R2 (1KB contiguous) -> exactly 1.0x. Model: the
// L2/HBM write path RMWs ~256B sectors on partial-sector writes. So: stage
// the whole 256B window in LDS, flush it in one full-sector store.
// NO min-waves launch-bounds (R3's (128,4) forced 64-VGPR cap -> spill hell).

constexpr int KH = 8, KW = 8, SH = 4, SW = 4;
constexpr int B = 8, C = 64, H = 96, W = 96;
constexpr int nH = (H - KH) / SH + 1;  // 23
constexpr int nW = (W - KW) / SW + 1;  // 23
constexpr int NWIN = B * C * nH * nW;  // 270848 = 128 * 2116
constexpr int TPB = 128;
constexpr int OSTRIDE = 65;            // 64 floats + 1 pad -> conflict-free

__global__ __launch_bounds__(TPB) void
local_autocorr_kernel(const float* __restrict__ x, float* __restrict__ out) {
    __shared__ float lds[TPB * OSTRIDE];  // 33280 B

    const int tid = threadIdx.x;
    const int n = blockIdx.x * TPB + tid;

    const int w  = n % nW;
    const int tt = n / nW;
    const int h  = tt % nH;
    const int bc = tt / nH;  // b*C + c

    const float* xp = x + ((size_t)bc * H + (size_t)h * SH) * W + (size_t)w * SW;

    // Load the 8x8 patch into registers (static indexing only).
    float p[64];
#pragma unroll
    for (int r = 0; r < 8; ++r) {
        const float4 lo = *reinterpret_cast<const float4*>(xp + (size_t)r * W);
        const float4 hi = *reinterpret_cast<const float4*>(xp + (size_t)r * W + 4);
        p[r * 8 + 0] = lo.x; p[r * 8 + 1] = lo.y;
        p[r * 8 + 2] = lo.z; p[r * 8 + 3] = lo.w;
        p[r * 8 + 4] = hi.x; p[r * 8 + 5] = hi.y;
        p[r * 8 + 6] = hi.z; p[r * 8 + 7] = hi.w;
    }

    // Compute all 8 dy rows; stash each in this window's LDS slot.
#pragma unroll
    for (int dy = 0; dy < 8; ++dy) {
        const int oy = dy - 4;  // compile-time after unroll
        float accs[8];
#pragma unroll
        for (int dx = 0; dx < 8; ++dx) {
            const int ox = dx - 4;
            float acc = 0.0f;
#pragma unroll
            for (int i = 0; i < 8; ++i) {
                if (i + oy < 0 || i + oy >= 8) continue;  // static DCE
#pragma unroll
                for (int j = 0; j < 8; ++j) {
                    if (j + ox < 0 || j + ox >= 8) continue;
                    acc = fmaf(p[(i + oy) * 8 + (j + ox)], p[i * 8 + j], acc);
                }
            }
            accs[dx] = acc;
        }
        *reinterpret_cast<float4*>(&lds[tid * OSTRIDE + dy * 8]) =
            make_float4(accs[0], accs[1], accs[2], accs[3]);
        *reinterpret_cast<float4*>(&lds[tid * OSTRIDE + dy * 8 + 4]) =
            make_float4(accs[4], accs[5], accs[6], accs[7]);
        // Contain accumulator liveness per dy row.
        __builtin_amdgcn_sched_barrier(0);
    }
    __syncthreads();

    // Flush: 128 windows x 16 float4 = 2048 slots, 16 per thread. Each wave
    // store instruction covers 4 complete 256B window regions (1KB contig).
    float* obase = out + (size_t)blockIdx.x * TPB * 64;
#pragma unroll
    for (int k = 0; k < 16; ++k) {
        const int flat4 = tid + k * TPB;   // 0..2047
        const int win   = flat4 >> 4;      // 0..127
        const int off4  = flat4 & 15;      // 0..15
        const float4 v = *reinterpret_cast<const float4*>(
            &lds[win * OSTRIDE + off4 * 4]);
        *reinterpret_cast<float4*>(obase + (size_t)win * 64 + off4 * 4) = v;
    }
}

extern "C" void kernel_launch(void* const* d_in, const int* in_sizes, int n_in,
                              void* d_out, int out_size, void* d_ws, size_t ws_size,
                              hipStream_t stream) {
    const float* x = (const float*)d_in[0];
    float* out = (float*)d_out;

    const int blocks = NWIN / TPB;  // 2116, exact
    local_autocorr_kernel<<<blocks, TPB, 0, stream>>>(x, out);
}

// Round 6
// 94.505 us; speedup vs baseline: 5.8461x; 1.2446x over previous
//
#include <hip/hip_runtime.h>

// Local 8x8 window autocorrelation, stride 4.
// x: (B, C, H, W) fp32 -> out: (B, C, nH, nW, KH, KW) fp32
// out[n, dy, dx] = sum_{i,j} p[i+dy-4][j+dx-4] * p[i][j]  (zero outside window)
//
// One thread per window. Evidence trail:
//  - R1/R4/R5 (fully-unrolled 2304-FMA body, p[64] in regs): VGPR_Count=256
//    (cap) + 136..247MB of EXTRA write traffic = scratch spill. sched_barrier
//    did not contain regalloc. R5's flush was full-sector-coalesced and still
//    showed 3.8x writes -> amplification is spill, not store-pattern RMW.
//  - R2 (small body, VGPR=92): WRITE_SIZE exactly = output size (67.7MB).
// Fix: static dy regions (exact static j guards -> 2304 FMAs, no padding
// waste) with a ROLLED i loop; operand rows re-loaded from global per (dy,i)
// (lane-consecutive 16B apart -> coalesced; overlap L1-absorbed). Live set
// ~40 VGPRs; no runtime register indexing anywhere -> no spill possible.
// Outputs staged in LDS, flushed as full 256B window regions (1KB contiguous
// per wave store instruction).

constexpr int KH = 8, KW = 8, SH = 4, SW = 4;
constexpr int B = 8, C = 64, H = 96, W = 96;
constexpr int nH = (H - KH) / SH + 1;  // 23
constexpr int nW = (W - KW) / SW + 1;  // 23
constexpr int NWIN = B * C * nH * nW;  // 270848 = 128 * 2116
constexpr int TPB = 128;
constexpr int OSTRIDE = 65;            // 64 floats + 1 pad

__global__ __launch_bounds__(TPB) void
local_autocorr_kernel(const float* __restrict__ x, float* __restrict__ out) {
    __shared__ float lds[TPB * OSTRIDE];  // 33280 B

    const int tid = threadIdx.x;
    const int n = blockIdx.x * TPB + tid;

    const int w  = n % nW;
    const int tt = n / nW;
    const int h  = tt % nH;
    const int bc = tt / nH;  // b*C + c

    const float* xp = x + ((size_t)bc * H + (size_t)h * SH) * W + (size_t)w * SW;

#pragma unroll
    for (int dy = 0; dy < 8; ++dy) {
        const int OY  = dy - 4;                   // compile-time after unroll
        const int ILO = (OY < 0) ? -OY : 0;
        const int IHI = (OY > 0) ? 8 - OY : 8;

        float accs[8] = {0.f, 0.f, 0.f, 0.f, 0.f, 0.f, 0.f, 0.f};

        // Rolled: keeps the live set at ~40 VGPRs (accs + a + b + pointers).
#pragma clang loop unroll(disable)
        for (int i = ILO; i < IHI; ++i) {
            const float* br = xp + (size_t)i * W;          // B row: P[i][*]
            const float* ar = br + (ptrdiff_t)OY * W;      // A row: P[i+OY][*]

            const float4 b0 = *reinterpret_cast<const float4*>(br);
            const float4 b1 = *reinterpret_cast<const float4*>(br + 4);
            const float4 a0 = *reinterpret_cast<const float4*>(ar);
            const float4 a1 = *reinterpret_cast<const float4*>(ar + 4);
            const float b[8] = {b0.x, b0.y, b0.z, b0.w, b1.x, b1.y, b1.z, b1.w};
            const float a[8] = {a0.x, a0.y, a0.z, a0.w, a1.x, a1.y, a1.z, a1.w};

#pragma unroll
            for (int dx = 0; dx < 8; ++dx) {
                const int OX = dx - 4;
#pragma unroll
                for (int j = 0; j < 8; ++j) {
                    if (j + OX < 0 || j + OX >= 8) continue;  // static DCE
                    accs[dx] = fmaf(a[j + OX], b[j], accs[dx]);
                }
            }
        }

        *reinterpret_cast<float4*>(&lds[tid * OSTRIDE + dy * 8]) =
            make_float4(accs[0], accs[1], accs[2], accs[3]);
        *reinterpret_cast<float4*>(&lds[tid * OSTRIDE + dy * 8 + 4]) =
            make_float4(accs[4], accs[5], accs[6], accs[7]);
    }
    __syncthreads();

    // Flush: 128 windows x 16 float4 = 2048 slots, 16 per thread. Each wave
    // store instruction covers 4 complete 256B window regions (1KB contig).
    float* obase = out + (size_t)blockIdx.x * TPB * 64;
#pragma unroll
    for (int k = 0; k < 16; ++k) {
        const int flat4 = tid + k * TPB;   // 0..2047
        const int win   = flat4 >> 4;      // 0..127
        const int off4  = flat4 & 15;      // 0..15
        const float4 v = *reinterpret_cast<const float4*>(
            &lds[win * OSTRIDE + off4 * 4]);
        *reinterpret_cast<float4*>(obase + (size_t)win * 64 + off4 * 4) = v;
    }
}

extern "C" void kernel_launch(void* const* d_in, const int* in_sizes, int n_in,
                              void* d_out, int out_size, void* d_ws, size_t ws_size,
                              hipStream_t stream) {
    const float* x = (const float*)d_in[0];
    float* out = (float*)d_out;

    const int blocks = NWIN / TPB;  // 2116, exact
    local_autocorr_kernel<<<blocks, TPB, 0, stream>>>(x, out);
}

// Round 7
// 47.681 us; speedup vs baseline: 11.5871x; 1.9820x over previous
//
#include <hip/hip_runtime.h>

// Local 8x8 window autocorrelation, stride 4.
// x: (B, C, H, W) fp32 -> out: (B, C, nH, nW, KH, KW) fp32
// out[n, dy, dx] = sum_{i,j} p[i+dy-4][j+dx-4] * p[i][j]  (zero outside window)
//
// One thread per window; rows re-loaded from global per (dy,i) (coalesced,
// L1/L2-resident; avoids p[64]-in-regs which spilled at VGPR=256 in R1/R4/R5).
// Outputs staged in LDS, flushed as full 256B window regions.
// R6 was byte-exact on traffic (WRITE=67.7MB) but latency-bound at 16%
// occupancy (33KB LDS -> 4 blocks/CU) with a serial load->FMA loop.
// R7: TPB=64 (LDS 16.6KB -> 9 blocks/CU), i-loop unroll(2) (8 loads in
// flight), and central symmetry corr(-oy,-ox)=corr(oy,ox): compute rows
// dy=0..4 only, mirror rows 5..7 (dx>=1) from rows 3..1 reversed; the three
// (dy in 5..7, dx=0) cells fold into rows 1..3's loops (same row pair,
// roles swapped) at zero extra load rounds. FMA 2304->1512, rounds 48->30.

constexpr int KH = 8, KW = 8, SH = 4, SW = 4;
constexpr int B = 8, C = 64, H = 96, W = 96;
constexpr int nH = (H - KH) / SH + 1;  // 23
constexpr int nW = (W - KW) / SW + 1;  // 23
constexpr int NWIN = B * C * nH * nW;  // 270848 = 64 * 4232
constexpr int TPB = 64;
constexpr int OSTRIDE = 65;            // 64 floats + 1 pad

__global__ __launch_bounds__(TPB) void
local_autocorr_kernel(const float* __restrict__ x, float* __restrict__ out) {
    __shared__ float lds[TPB * OSTRIDE];  // 16640 B

    const int tid = threadIdx.x;
    const int n = blockIdx.x * TPB + tid;

    const int w  = n % nW;
    const int tt = n / nW;
    const int h  = tt % nH;
    const int bc = tt / nH;  // b*C + c

    const float* xp = x + ((size_t)bc * H + (size_t)h * SH) * W + (size_t)w * SW;

    float acc50 = 0.f, acc60 = 0.f, acc70 = 0.f;  // cells (5,0),(6,0),(7,0)

#pragma unroll
    for (int dy = 0; dy < 5; ++dy) {
        const int OY  = dy - 4;        // -4..0, compile-time after unroll
        const int ILO = -OY;           // first valid i

        float accs[8] = {0.f, 0.f, 0.f, 0.f, 0.f, 0.f, 0.f, 0.f};

#pragma unroll 2
        for (int i = ILO; i < 8; ++i) {
            const float* br = xp + (size_t)i * W;       // B row: P[i][*]
            const float* ar = br + (ptrdiff_t)OY * W;   // A row: P[i+OY][*]

            const float4 b0 = *reinterpret_cast<const float4*>(br);
            const float4 b1 = *reinterpret_cast<const float4*>(br + 4);
            const float4 a0 = *reinterpret_cast<const float4*>(ar);
            const float4 a1 = *reinterpret_cast<const float4*>(ar + 4);
            const float b[8] = {b0.x, b0.y, b0.z, b0.w, b1.x, b1.y, b1.z, b1.w};
            const float a[8] = {a0.x, a0.y, a0.z, a0.w, a1.x, a1.y, a1.z, a1.w};

#pragma unroll
            for (int dx = 0; dx < 8; ++dx) {
                const int OX = dx - 4;
#pragma unroll
                for (int j = 0; j < 8; ++j) {
                    if (j + OX < 0 || j + OX >= 8) continue;  // static DCE
                    accs[dx] = fmaf(a[j + OX], b[j], accs[dx]);
                }
            }

            // Fold cell (8-dy, 0) into this row pair (oy' = -OY, ox' = -4):
            // out[8-dy][0] = sum_{j=0..3} b[j] * a[j+4]
            if (dy == 1) {
                acc70 = fmaf(b[0], a[4], acc70); acc70 = fmaf(b[1], a[5], acc70);
                acc70 = fmaf(b[2], a[6], acc70); acc70 = fmaf(b[3], a[7], acc70);
            } else if (dy == 2) {
                acc60 = fmaf(b[0], a[4], acc60); acc60 = fmaf(b[1], a[5], acc60);
                acc60 = fmaf(b[2], a[6], acc60); acc60 = fmaf(b[3], a[7], acc60);
            } else if (dy == 3) {
                acc50 = fmaf(b[0], a[4], acc50); acc50 = fmaf(b[1], a[5], acc50);
                acc50 = fmaf(b[2], a[6], acc50); acc50 = fmaf(b[3], a[7], acc50);
            }
        }

        // Direct row write.
        *reinterpret_cast<float4*>(&lds[tid * OSTRIDE + dy * 8]) =
            make_float4(accs[0], accs[1], accs[2], accs[3]);
        *reinterpret_cast<float4*>(&lds[tid * OSTRIDE + dy * 8 + 4]) =
            make_float4(accs[4], accs[5], accs[6], accs[7]);

        // Mirror row 8-dy (dy=1..3 -> rows 7,6,5): out[8-dy][dx] = accs[8-dx].
        if (dy >= 1 && dy <= 3) {
            const int mrow = (8 - dy) * 8;
#pragma unroll
            for (int dx = 1; dx < 8; ++dx) {
                lds[tid * OSTRIDE + mrow + dx] = accs[8 - dx];
            }
        }
    }

    // The three folded cells.
    lds[tid * OSTRIDE + 5 * 8] = acc50;
    lds[tid * OSTRIDE + 6 * 8] = acc60;
    lds[tid * OSTRIDE + 7 * 8] = acc70;

    __syncthreads();

    // Flush: 64 windows x 16 float4 = 1024 slots, 16 per thread. Each wave
    // store instruction covers 4 complete 256B window regions (1KB contig).
    float* obase = out + (size_t)blockIdx.x * TPB * 64;
#pragma unroll
    for (int k = 0; k < 16; ++k) {
        const int flat4 = tid + k * TPB;   // 0..1023
        const int win   = flat4 >> 4;      // 0..63
        const int off4  = flat4 & 15;      // 0..15
        const float4 v = *reinterpret_cast<const float4*>(
            &lds[win * OSTRIDE + off4 * 4]);
        *reinterpret_cast<float4*>(obase + (size_t)win * 64 + off4 * 4) = v;
    }
}

extern "C" void kernel_launch(void* const* d_in, const int* in_sizes, int n_in,
                              void* d_out, int out_size, void* d_ws, size_t ws_size,
                              hipStream_t stream) {
    const float* x = (const float*)d_in[0];
    float* out = (float*)d_out;

    const int blocks = NWIN / TPB;  // 4232, exact
    local_autocorr_kernel<<<blocks, TPB, 0, stream>>>(x, out);
}

// Round 8
// 37.737 us; speedup vs baseline: 14.6405x; 1.2635x over previous
//
#include <hip/hip_runtime.h>

// Local 8x8 window autocorrelation, stride 4.
// x: (B, C, H, W) fp32 -> out: (B, C, nH, nW, KH, KW) fp32
// out[n, dy, dx] = sum_{i,j} p[i+dy-4][j+dx-4] * p[i][j]  (zero outside window)
//
// One thread per window. R8: sliding-row structure — each patch row is
// loaded from global ONCE (16 float4/thread vs R7's 120): at step r,
// prefetch row r+1, then accumulate all pairs (r-d, r), d=0..4, into the
// dy=4-d accumulator row (+ folded (4+d,0) cells). R7 measured 90% per-wave
// stall on L2/L3 latency from the 30 reload rounds (L1 thrashes at 96KB
// working set); this removes 7.5x of the loads. FMA count unchanged (1512,
// central symmetry: rows 5..7 dx>=1 mirrored from rows 3..1).
// All register indices compile-time static (rule #20). sched_barrier(0) per
// r-step contains scheduler fusion (R1/R4/R5 ballooned to VGPR=256 + spill).
// Outputs staged in LDS, flushed as full 256B window regions (1KB contiguous
// per wave store instruction) — R2/R6/R7 proved byte-exact write traffic;
// partial-sector stores cost 3-4.7x (R1/R4).

constexpr int KH = 8, KW = 8, SH = 4, SW = 4;
constexpr int B = 8, C = 64, H = 96, W = 96;
constexpr int nH = (H - KH) / SH + 1;  // 23
constexpr int nW = (W - KW) / SW + 1;  // 23
constexpr int NWIN = B * C * nH * nW;  // 270848 = 64 * 4232
constexpr int TPB = 64;
constexpr int OSTRIDE = 65;            // 64 floats + 1 pad

__global__ __launch_bounds__(TPB) void
local_autocorr_kernel(const float* __restrict__ x, float* __restrict__ out) {
    __shared__ float lds[TPB * OSTRIDE];  // 16640 B

    const int tid = threadIdx.x;
    const int n = blockIdx.x * TPB + tid;

    const int w  = n % nW;
    const int tt = n / nW;
    const int h  = tt % nH;
    const int bc = tt / nH;  // b*C + c

    const float* xp = x + ((size_t)bc * H + (size_t)h * SH) * W + (size_t)w * SW;

    float rows[8][8];       // row r live only for steps r..r+4 (compiler sees it)
    float acc[5][8];        // dy = 0..4
    float acc50 = 0.f, acc60 = 0.f, acc70 = 0.f;  // cells (5,0),(6,0),(7,0)
#pragma unroll
    for (int dy = 0; dy < 5; ++dy)
#pragma unroll
        for (int dx = 0; dx < 8; ++dx) acc[dy][dx] = 0.f;

    // Prologue: load row 0.
    {
        const float4 lo = *reinterpret_cast<const float4*>(xp);
        const float4 hi = *reinterpret_cast<const float4*>(xp + 4);
        rows[0][0] = lo.x; rows[0][1] = lo.y; rows[0][2] = lo.z; rows[0][3] = lo.w;
        rows[0][4] = hi.x; rows[0][5] = hi.y; rows[0][6] = hi.z; rows[0][7] = hi.w;
    }

#pragma unroll
    for (int r = 0; r < 8; ++r) {
        // Prefetch row r+1 (latency covered by this step's FMA block).
        if (r < 7) {
            const float4 lo = *reinterpret_cast<const float4*>(xp + (size_t)(r + 1) * W);
            const float4 hi = *reinterpret_cast<const float4*>(xp + (size_t)(r + 1) * W + 4);
            rows[r + 1][0] = lo.x; rows[r + 1][1] = lo.y;
            rows[r + 1][2] = lo.z; rows[r + 1][3] = lo.w;
            rows[r + 1][4] = hi.x; rows[r + 1][5] = hi.y;
            rows[r + 1][6] = hi.z; rows[r + 1][7] = hi.w;
        }

        const int DMAX = (r < 4) ? r : 4;
#pragma unroll
        for (int d = 0; d <= DMAX; ++d) {
            // Pair (i-d, i) with i = r: b = P[i] = rows[r], a = P[i-d] = rows[r-d].
            // Contributes to dy = 4-d (OY = -d).
            const int dy = 4 - d;
#pragma unroll
            for (int dx = 0; dx < 8; ++dx) {
                const int OX = dx - 4;
#pragma unroll
                for (int j = 0; j < 8; ++j) {
                    if (j + OX < 0 || j + OX >= 8) continue;  // static DCE
                    acc[dy][dx] = fmaf(rows[r - d][j + OX], rows[r][j], acc[dy][dx]);
                }
            }
            // Folded cell (4+d, 0): out[4+d][0] += sum_{jj=0..3} b[jj]*a[jj+4].
            if (d == 1) {
                acc50 = fmaf(rows[r][0], rows[r - 1][4], acc50);
                acc50 = fmaf(rows[r][1], rows[r - 1][5], acc50);
                acc50 = fmaf(rows[r][2], rows[r - 1][6], acc50);
                acc50 = fmaf(rows[r][3], rows[r - 1][7], acc50);
            } else if (d == 2) {
                acc60 = fmaf(rows[r][0], rows[r - 2][4], acc60);
                acc60 = fmaf(rows[r][1], rows[r - 2][5], acc60);
                acc60 = fmaf(rows[r][2], rows[r - 2][6], acc60);
                acc60 = fmaf(rows[r][3], rows[r - 2][7], acc60);
            } else if (d == 3) {
                acc70 = fmaf(rows[r][0], rows[r - 3][4], acc70);
                acc70 = fmaf(rows[r][1], rows[r - 3][5], acc70);
                acc70 = fmaf(rows[r][2], rows[r - 3][6], acc70);
                acc70 = fmaf(rows[r][3], rows[r - 3][7], acc70);
            }
        }
        // Contain scheduler fusion / register ballooning across r-steps.
        __builtin_amdgcn_sched_barrier(0);
    }

    // Stage this window's 64 outputs in LDS.
#pragma unroll
    for (int dy = 0; dy < 5; ++dy) {
        *reinterpret_cast<float4*>(&lds[tid * OSTRIDE + dy * 8]) =
            make_float4(acc[dy][0], acc[dy][1], acc[dy][2], acc[dy][3]);
        *reinterpret_cast<float4*>(&lds[tid * OSTRIDE + dy * 8 + 4]) =
            make_float4(acc[dy][4], acc[dy][5], acc[dy][6], acc[dy][7]);
    }
    // Mirror rows 5..7 (dx>=1): out[8-dy][dx] = acc[dy][8-dx], dy=3..1.
#pragma unroll
    for (int dy = 1; dy <= 3; ++dy) {
        const int mrow = (8 - dy) * 8;
#pragma unroll
        for (int dx = 1; dx < 8; ++dx) {
            lds[tid * OSTRIDE + mrow + dx] = acc[dy][8 - dx];
        }
    }
    lds[tid * OSTRIDE + 5 * 8] = acc50;
    lds[tid * OSTRIDE + 6 * 8] = acc60;
    lds[tid * OSTRIDE + 7 * 8] = acc70;

    __syncthreads();

    // Flush: 64 windows x 16 float4 = 1024 slots, 16 per thread. Each wave
    // store instruction covers 4 complete 256B window regions (1KB contig).
    float* obase = out + (size_t)blockIdx.x * TPB * 64;
#pragma unroll
    for (int k = 0; k < 16; ++k) {
        const int flat4 = tid + k * TPB;   // 0..1023
        const int win   = flat4 >> 4;      // 0..63
        const int off4  = flat4 & 15;      // 0..15
        const float4 v = *reinterpret_cast<const float4*>(
            &lds[win * OSTRIDE + off4 * 4]);
        *reinterpret_cast<float4*>(obase + (size_t)win * 64 + off4 * 4) = v;
    }
}

extern "C" void kernel_launch(void* const* d_in, const int* in_sizes, int n_in,
                              void* d_out, int out_size, void* d_ws, size_t ws_size,
                              hipStream_t stream) {
    const float* x = (const float*)d_in[0];
    float* out = (float*)d_out;

    const int blocks = NWIN / TPB;  // 4232, exact
    local_autocorr_kernel<<<blocks, TPB, 0, stream>>>(x, out);
}

// Round 9
// 31.377 us; speedup vs baseline: 17.6082x; 1.2027x over previous
//
#include <hip/hip_runtime.h>

// Local 8x8 window autocorrelation, stride 4.
// x: (B, C, H, W) fp32 -> out: (B, C, nH, nW, KH, KW) fp32
// out[n, dy, dx] = sum_{i,j} p[i+dy-4][j+dx-4] * p[i][j]  (zero outside window)
//
// One thread per window, sliding-row streaming (each row loaded once per
// pass), central symmetry (1512 FMA). R8 was correct+byte-exact but
// VGPR=180 -> ~2.5 waves/CU residency, 75% per-wave stall.
// R9 cuts both occupancy caps:
//  - Two-pass d-split: pass A d=0..2 (4 rows live), pass B d=3..4 (6 rows
//    live) instead of all 8 rows live. asm memory clobber between passes
//    blocks cross-pass CSE (pass B reloads rows; L1/L2-hot).
//  - Two-phase flush: 32-window LDS slab (8.3KB vs 16.6KB); each phase
//    flushes an 8KB CONTIGUOUS region via 1KB full-sector wave stores
//    (write-amp trap only bites for partial 256B sectors - R1/R4 evidence).
//  - __launch_bounds__(64,2): bounds allocator near 128 VGPR (empirically
//    cap=256/w from R3; or 512/w = no-op - safe under both).

constexpr int KH = 8, KW = 8, SH = 4, SW = 4;
constexpr int B = 8, C = 64, H = 96, W = 96;
constexpr int nH = (H - KH) / SH + 1;  // 23
constexpr int nW = (W - KW) / SW + 1;  // 23
constexpr int NWIN = B * C * nH * nW;  // 270848 = 64 * 4232
constexpr int TPB = 64;
constexpr int HALFW = 32;              // windows staged per flush phase
constexpr int OSTRIDE = 65;            // 64 floats + 1 pad

__global__ __launch_bounds__(TPB, 2) void
local_autocorr_kernel(const float* __restrict__ x, float* __restrict__ out) {
    __shared__ float lds[HALFW * OSTRIDE];  // 8320 B

    const int tid = threadIdx.x;
    const int n = blockIdx.x * TPB + tid;

    const int w  = n % nW;
    const int tt = n / nW;
    const int h  = tt % nH;
    const int bc = tt / nH;  // b*C + c

    const float* xp = x + ((size_t)bc * H + (size_t)h * SH) * W + (size_t)w * SW;

    float accA[3][8];   // accA[d] -> dy = 4-d, d = 0..2
    float c50 = 0.f, c60 = 0.f, c70 = 0.f;  // cells (5,0),(6,0),(7,0)
#pragma unroll
    for (int k = 0; k < 3; ++k)
#pragma unroll
        for (int dx = 0; dx < 8; ++dx) accA[k][dx] = 0.f;

    // ---- Pass A: d = 0..2 (rows r-2 .. r+1 live) ----
    {
        float rows[8][8];
        {
            const float4 lo = *reinterpret_cast<const float4*>(xp);
            const float4 hi = *reinterpret_cast<const float4*>(xp + 4);
            rows[0][0]=lo.x; rows[0][1]=lo.y; rows[0][2]=lo.z; rows[0][3]=lo.w;
            rows[0][4]=hi.x; rows[0][5]=hi.y; rows[0][6]=hi.z; rows[0][7]=hi.w;
        }
#pragma unroll
        for (int r = 0; r < 8; ++r) {
            if (r < 7) {
                const float4 lo = *reinterpret_cast<const float4*>(xp + (size_t)(r+1)*W);
                const float4 hi = *reinterpret_cast<const float4*>(xp + (size_t)(r+1)*W + 4);
                rows[r+1][0]=lo.x; rows[r+1][1]=lo.y; rows[r+1][2]=lo.z; rows[r+1][3]=lo.w;
                rows[r+1][4]=hi.x; rows[r+1][5]=hi.y; rows[r+1][6]=hi.z; rows[r+1][7]=hi.w;
            }
#pragma unroll
            for (int d = 0; d <= 2; ++d) {
                if (d > r) continue;  // static after unroll
#pragma unroll
                for (int dx = 0; dx < 8; ++dx) {
                    const int OX = dx - 4;
#pragma unroll
                    for (int j = 0; j < 8; ++j) {
                        if (j + OX < 0 || j + OX >= 8) continue;  // static DCE
                        accA[d][dx] = fmaf(rows[r-d][j+OX], rows[r][j], accA[d][dx]);
                    }
                }
                if (d == 1) {
                    c50 = fmaf(rows[r][0], rows[r-1][4], c50);
                    c50 = fmaf(rows[r][1], rows[r-1][5], c50);
                    c50 = fmaf(rows[r][2], rows[r-1][6], c50);
                    c50 = fmaf(rows[r][3], rows[r-1][7], c50);
                } else if (d == 2) {
                    c60 = fmaf(rows[r][0], rows[r-2][4], c60);
                    c60 = fmaf(rows[r][1], rows[r-2][5], c60);
                    c60 = fmaf(rows[r][2], rows[r-2][6], c60);
                    c60 = fmaf(rows[r][3], rows[r-2][7], c60);
                }
            }
            __builtin_amdgcn_sched_barrier(0);
        }
    }

    // Block cross-pass CSE: pass B must reload its rows (frees pass A's).
    asm volatile("" ::: "memory");

    float accB[2][8];   // accB[d-3] -> dy = 4-d, d = 3..4
#pragma unroll
    for (int k = 0; k < 2; ++k)
#pragma unroll
        for (int dx = 0; dx < 8; ++dx) accB[k][dx] = 0.f;

    // ---- Pass B: d = 3..4 (rows r-4 .. r+1 live) ----
    {
        float rows[8][8];
#pragma unroll
        for (int k = 0; k < 4; ++k) {
            const float4 lo = *reinterpret_cast<const float4*>(xp + (size_t)k*W);
            const float4 hi = *reinterpret_cast<const float4*>(xp + (size_t)k*W + 4);
            rows[k][0]=lo.x; rows[k][1]=lo.y; rows[k][2]=lo.z; rows[k][3]=lo.w;
            rows[k][4]=hi.x; rows[k][5]=hi.y; rows[k][6]=hi.z; rows[k][7]=hi.w;
        }
#pragma unroll
        for (int r = 3; r < 8; ++r) {
            if (r < 7) {
                const float4 lo = *reinterpret_cast<const float4*>(xp + (size_t)(r+1)*W);
                const float4 hi = *reinterpret_cast<const float4*>(xp + (size_t)(r+1)*W + 4);
                rows[r+1][0]=lo.x; rows[r+1][1]=lo.y; rows[r+1][2]=lo.z; rows[r+1][3]=lo.w;
                rows[r+1][4]=hi.x; rows[r+1][5]=hi.y; rows[r+1][6]=hi.z; rows[r+1][7]=hi.w;
            }
#pragma unroll
            for (int d = 3; d <= 4; ++d) {
                if (d > r) continue;  // static after unroll
#pragma unroll
                for (int dx = 0; dx < 8; ++dx) {
                    const int OX = dx - 4;
#pragma unroll
                    for (int j = 0; j < 8; ++j) {
                        if (j + OX < 0 || j + OX >= 8) continue;  // static DCE
                        accB[d-3][dx] = fmaf(rows[r-d][j+OX], rows[r][j], accB[d-3][dx]);
                    }
                }
                if (d == 3) {
                    c70 = fmaf(rows[r][0], rows[r-3][4], c70);
                    c70 = fmaf(rows[r][1], rows[r-3][5], c70);
                    c70 = fmaf(rows[r][2], rows[r-3][6], c70);
                    c70 = fmaf(rows[r][3], rows[r-3][7], c70);
                }
            }
            __builtin_amdgcn_sched_barrier(0);
        }
    }

    // ---- Two-phase stage + flush (8KB contiguous, full-sector stores) ----
    float* obase = out + (size_t)blockIdx.x * TPB * 64;
#pragma unroll
    for (int ph = 0; ph < 2; ++ph) {
        if ((tid >> 5) == ph) {
            float* slot = &lds[(tid & 31) * OSTRIDE];
            // rows dy = 0..4 direct; 5..7 = mirror + folded cell.
            *reinterpret_cast<float4*>(slot + 0)  = make_float4(accB[1][0], accB[1][1], accB[1][2], accB[1][3]);
            *reinterpret_cast<float4*>(slot + 4)  = make_float4(accB[1][4], accB[1][5], accB[1][6], accB[1][7]);
            *reinterpret_cast<float4*>(slot + 8)  = make_float4(accB[0][0], accB[0][1], accB[0][2], accB[0][3]);
            *reinterpret_cast<float4*>(slot + 12) = make_float4(accB[0][4], accB[0][5], accB[0][6], accB[0][7]);
            *reinterpret_cast<float4*>(slot + 16) = make_float4(accA[2][0], accA[2][1], accA[2][2], accA[2][3]);
            *reinterpret_cast<float4*>(slot + 20) = make_float4(accA[2][4], accA[2][5], accA[2][6], accA[2][7]);
            *reinterpret_cast<float4*>(slot + 24) = make_float4(accA[1][0], accA[1][1], accA[1][2], accA[1][3]);
            *reinterpret_cast<float4*>(slot + 28) = make_float4(accA[1][4], accA[1][5], accA[1][6], accA[1][7]);
            *reinterpret_cast<float4*>(slot + 32) = make_float4(accA[0][0], accA[0][1], accA[0][2], accA[0][3]);
            *reinterpret_cast<float4*>(slot + 36) = make_float4(accA[0][4], accA[0][5], accA[0][6], accA[0][7]);
            *reinterpret_cast<float4*>(slot + 40) = make_float4(c50,        accA[1][7], accA[1][6], accA[1][5]);
            *reinterpret_cast<float4*>(slot + 44) = make_float4(accA[1][4], accA[1][3], accA[1][2], accA[1][1]);
            *reinterpret_cast<float4*>(slot + 48) = make_float4(c60,        accA[2][7], accA[2][6], accA[2][5]);
            *reinterpret_cast<float4*>(slot + 52) = make_float4(accA[2][4], accA[2][3], accA[2][2], accA[2][1]);
            *reinterpret_cast<float4*>(slot + 56) = make_float4(c70,        accB[0][7], accB[0][6], accB[0][5]);
            *reinterpret_cast<float4*>(slot + 60) = make_float4(accB[0][4], accB[0][3], accB[0][2], accB[0][1]);
        }
        __syncthreads();
        // Flush 32 windows x 16 float4 = 512 slots, 8 per thread; each wave
        // store covers 1KB contiguous (4 complete 256B window regions), and
        // the phase covers one 8KB contiguous span.
#pragma unroll
        for (int k = 0; k < 8; ++k) {
            const int flat4 = tid + k * 64;    // 0..511
            const float4 v = *reinterpret_cast<const float4*>(
                &lds[(flat4 >> 4) * OSTRIDE + (flat4 & 15) * 4]);
            *reinterpret_cast<float4*>(obase + (size_t)ph * HALFW * 64 + flat4 * 4) = v;
        }
        __syncthreads();  // WAR: protect LDS before next phase restages
    }
}

extern "C" void kernel_launch(void* const* d_in, const int* in_sizes, int n_in,
                              void* d_out, int out_size, void* d_ws, size_t ws_size,
                              hipStream_t stream) {
    const float* x = (const float*)d_in[0];
    float* out = (float*)d_out;

    const int blocks = NWIN / TPB;  // 4232, exact
    local_autocorr_kernel<<<blocks, TPB, 0, stream>>>(x, out);
}